// Round 1
// baseline (332.030 us; speedup 1.0000x reference)
//
#include <hip/hip_runtime.h>
#include <stdint.h>

#define DIM 256
#define HID 256
#define NSEQ 512
#define NB 2
#define EPS 1e-5f

typedef __attribute__((ext_vector_type(4))) float f32x4;
typedef __attribute__((ext_vector_type(2))) int   i32x2;

__device__ __forceinline__ unsigned short f2bf(float f) {
    unsigned int u = __float_as_uint(f);
    u += 0x7fffu + ((u >> 16) & 1u);
    return (unsigned short)(u >> 16);
}

__device__ __forceinline__ float gelu_exact(float x) {
    return 0.5f * x * (1.0f + erff(x * 0.7071067811865476f));
}

// Robustly determine whether mask bools arrive as int32 (one per element)
// or as packed uint8. Reads only 1024 bytes (safe under both layouts).
__global__ void detect_mask_kernel(const int* __restrict__ m, int* __restrict__ flag) {
    __shared__ int bad_s[4];
    const int t = threadIdx.x;
    int v = m[t];                       // 256 ints = 1024 B
    unsigned long long bm = __ballot((v & ~1) != 0);
    if ((t & 63) == 0) bad_s[t >> 6] = (bm != 0ull) ? 1 : 0;
    __syncthreads();
    if (t == 0) flag[0] = bad_s[0] | bad_s[1] | bad_s[2] | bad_s[3];
}

// One block per (b,n) row: LayerNorm(x) @ Wl + bl, then apply mask -> lm (f32)
__global__ __launch_bounds__(256) void ln_left_kernel(
    const float* __restrict__ x, const void* __restrict__ mask,
    const float* __restrict__ ln_g, const float* __restrict__ ln_b,
    const float* __restrict__ Wl, const float* __restrict__ bl,
    const int* __restrict__ flag, float* __restrict__ lm)
{
    const int row = blockIdx.x;          // b*NSEQ + n
    const int t = threadIdx.x;
    const int lane = t & 63, w = t >> 6;
    __shared__ float xs[DIM];
    __shared__ float red[8];

    float v = x[row * DIM + t];
    float s = v, ss = v * v;
    #pragma unroll
    for (int o = 32; o; o >>= 1) { s += __shfl_xor(s, o); ss += __shfl_xor(ss, o); }
    if (lane == 0) { red[w] = s; red[4 + w] = ss; }
    __syncthreads();
    s  = red[0] + red[1] + red[2] + red[3];
    ss = red[4] + red[5] + red[6] + red[7];
    const float mu  = s * (1.0f / DIM);
    const float var = ss * (1.0f / DIM) - mu * mu;
    const float rs  = rsqrtf(var + EPS);
    xs[t] = (v - mu) * rs * ln_g[t] + ln_b[t];
    __syncthreads();

    float acc = bl[t];
    #pragma unroll 4
    for (int k = 0; k < DIM; k += 4) {
        float4 xv = *(const float4*)&xs[k];
        acc = fmaf(xv.x, Wl[(k + 0) * HID + t], acc);
        acc = fmaf(xv.y, Wl[(k + 1) * HID + t], acc);
        acc = fmaf(xv.z, Wl[(k + 2) * HID + t], acc);
        acc = fmaf(xv.w, Wl[(k + 3) * HID + t], acc);
    }
    const int mv = flag[0] ? (int)((const unsigned char*)mask)[row]
                           : ((const int*)mask)[row];
    lm[row * HID + t] = mv ? acc : 0.0f;
}

// WoT[n][k] = bf16(Wo[k][n])
__global__ __launch_bounds__(256) void wo_transpose_kernel(
    const float* __restrict__ Wo, unsigned short* __restrict__ woT)
{
    const int n = blockIdx.x, k = threadIdx.x;
    woT[n * HID + k] = f2bf(Wo[k * HID + n]);
}

// Main fused kernel: block = (b, i, 64-row j tile).
// Phase A: 64 rows of gelu(lm_i*lm_j) + LN -> bf16 tile in XOR-swizzled LDS.
// Phase B: 4 waves, each computes a 64x64 output chunk via mfma 16x16x16 bf16.
__global__ __launch_bounds__(256) void outer_kernel(
    const float* __restrict__ lm, const unsigned short* __restrict__ woT,
    const float* __restrict__ lno_g, const float* __restrict__ lno_b,
    const float* __restrict__ bo, float* __restrict__ out)
{
    const int blk = blockIdx.x;
    const int b   = blk >> 12;            // 4096 blocks per batch
    const int i   = (blk >> 3) & (NSEQ - 1);
    const int jt  = blk & 7;
    const int j0  = jt * 64;
    const int t    = threadIdx.x;
    const int lane = t & 63;
    const int w    = t >> 6;

    __shared__ __align__(16) unsigned char ybuf[64 * 512];  // 64 rows x 256 bf16

    const float4 li4 = *(const float4*)&lm[(size_t)(b * NSEQ + i) * HID + lane * 4];
    const float4 g4  = *(const float4*)&lno_g[lane * 4];
    const float4 bb4 = *(const float4*)&lno_b[lane * 4];

    // ---------------- Phase A: wave w handles local rows [16w, 16w+16)
    for (int r = 0; r < 16; ++r) {
        const int rl = w * 16 + r;
        const int j  = j0 + rl;
        float4 lj4 = *(const float4*)&lm[(size_t)(b * NSEQ + j) * HID + lane * 4];
        float4 p;
        p.x = gelu_exact(li4.x * lj4.x);
        p.y = gelu_exact(li4.y * lj4.y);
        p.z = gelu_exact(li4.z * lj4.z);
        p.w = gelu_exact(li4.w * lj4.w);
        float s  = p.x + p.y + p.z + p.w;
        float ss = p.x * p.x + p.y * p.y + p.z * p.z + p.w * p.w;
        #pragma unroll
        for (int o = 32; o; o >>= 1) { s += __shfl_xor(s, o); ss += __shfl_xor(ss, o); }
        const float mu  = s * (1.0f / HID);
        const float var = ss * (1.0f / HID) - mu * mu;
        const float rs  = rsqrtf(var + EPS);
        const float y0 = (p.x - mu) * rs * g4.x + bb4.x;
        const float y1 = (p.y - mu) * rs * g4.y + bb4.y;
        const float y2 = (p.z - mu) * rs * g4.z + bb4.z;
        const float y3 = (p.w - mu) * rs * g4.w + bb4.w;
        const unsigned int u0 = ((unsigned)f2bf(y1) << 16) | (unsigned)f2bf(y0);
        const unsigned int u1 = ((unsigned)f2bf(y3) << 16) | (unsigned)f2bf(y2);
        // XOR swizzle: flip byte bits 4..6 with (row&7) to kill 512B-stride bank conflicts
        const int off = rl * 512 + ((lane * 8) ^ ((rl & 7) << 4));
        *(uint2*)&ybuf[off] = make_uint2(u0, u1);
    }
    __syncthreads();

    // ---------------- Phase B: wave w owns output cols [64w, 64w+64)
    const int n0  = w * 64;
    const int l15 = lane & 15;
    const int q   = lane >> 4;           // 0..3

    f32x4 acc[4][4];
    #pragma unroll
    for (int mi = 0; mi < 4; ++mi)
        #pragma unroll
        for (int ni = 0; ni < 4; ++ni)
            acc[mi][ni] = (f32x4){0.f, 0.f, 0.f, 0.f};

    #pragma unroll
    for (int kk = 0; kk < 16; ++kk) {          // K = 256 in steps of 16
        const int koff = kk * 32 + q * 8;      // byte offset in row: k elems kk*16 + 4q
        i32x2 a[4], bf[4];
        #pragma unroll
        for (int mi = 0; mi < 4; ++mi) {
            const int rowm = mi * 16 + l15;
            a[mi] = *(const i32x2*)&ybuf[rowm * 512 + (koff ^ ((rowm & 7) << 4))];
        }
        const int kel = kk * 16 + q * 4;
        #pragma unroll
        for (int ni = 0; ni < 4; ++ni) {
            const int col = n0 + ni * 16 + l15;
            bf[ni] = *(const i32x2*)&woT[col * HID + kel];
        }
        #pragma unroll
        for (int mi = 0; mi < 4; ++mi)
            #pragma unroll
            for (int ni = 0; ni < 4; ++ni)
                asm("v_mfma_f32_16x16x16_bf16 %0, %1, %2, %0"
                    : "+v"(acc[mi][ni]) : "v"(a[mi]), "v"(bf[ni]));
    }

    asm volatile("s_nop 7" ::: "memory");
    asm volatile("s_nop 7" ::: "memory");

    // Epilogue: C/D layout col = lane&15, row = 4*(lane>>4) + reg
    const size_t base = (size_t)(b * NSEQ + i) * NSEQ * HID;
    #pragma unroll
    for (int ni = 0; ni < 4; ++ni) {
        const int col = n0 + ni * 16 + l15;
        const float boc = bo[col];
        #pragma unroll
        for (int mi = 0; mi < 4; ++mi) {
            const int rbase = j0 + mi * 16 + q * 4;
            #pragma unroll
            for (int rr = 0; rr < 4; ++rr) {
                out[base + (size_t)(rbase + rr) * HID + col] = acc[mi][ni][rr] + boc;
            }
        }
    }
}

extern "C" void kernel_launch(void* const* d_in, const int* in_sizes, int n_in,
                              void* d_out, int out_size, void* d_ws, size_t ws_size,
                              hipStream_t stream) {
    (void)in_sizes; (void)n_in; (void)out_size; (void)ws_size;
    const float* x     = (const float*)d_in[0];
    const void*  mask  = d_in[1];
    const float* ln_g  = (const float*)d_in[2];
    const float* ln_b  = (const float*)d_in[3];
    const float* Wl    = (const float*)d_in[4];
    const float* bl    = (const float*)d_in[5];
    const float* Wo    = (const float*)d_in[6];
    const float* bo    = (const float*)d_in[7];
    const float* lno_g = (const float*)d_in[8];
    const float* lno_b = (const float*)d_in[9];

    int*            flag = (int*)d_ws;
    float*          lm   = (float*)((char*)d_ws + 256);
    unsigned short* woT  = (unsigned short*)((char*)d_ws + 256 + (size_t)NB * NSEQ * HID * 4);

    detect_mask_kernel<<<1, 256, 0, stream>>>((const int*)mask, flag);
    ln_left_kernel<<<NB * NSEQ, 256, 0, stream>>>(x, mask, ln_g, ln_b, Wl, bl, flag, lm);
    wo_transpose_kernel<<<HID, 256, 0, stream>>>(Wo, woT);
    outer_kernel<<<NB * NSEQ * (NSEQ / 64), 256, 0, stream>>>(
        lm, woT, lno_g, lno_b, bo, (float*)d_out);
}

// Round 7
// 320.842 us; speedup vs baseline: 1.0349x; 1.0349x over previous
//
#include <hip/hip_runtime.h>
#include <stdint.h>

#define DIM 256
#define HID 256
#define NSEQ 512
#define NB 2
#define EPS 1e-5f

typedef __attribute__((ext_vector_type(4))) float f32x4;
typedef __attribute__((ext_vector_type(4))) short bf16x4;

// Blocks per batch: 512 diagonal (i, jt=i>>6) + 28 pairs * 64 rows = 2304
#define DIAG_BLOCKS 512
#define BATCH_BLOCKS 2304

__device__ __forceinline__ unsigned short f2bf(float f) {
    unsigned int u = __float_as_uint(f);
    u += 0x7fffu + ((u >> 16) & 1u);
    return (unsigned short)(u >> 16);
}

// Exact gelu (libm erff) — R1-proven numerics (absmax 0.0156).
__device__ __forceinline__ float gelu_exact(float x) {
    return 0.5f * x * (1.0f + erff(x * 0.7071067811865476f));
}

// Robustly determine whether mask bools arrive as int32 or packed uint8.
__global__ void detect_mask_kernel(const int* __restrict__ m, int* __restrict__ flag) {
    __shared__ int bad_s[4];
    const int t = threadIdx.x;
    int v = m[t];                       // 256 ints = 1024 B, safe under both layouts
    unsigned long long bm = __ballot((v & ~1) != 0);
    if ((t & 63) == 0) bad_s[t >> 6] = (bm != 0ull) ? 1 : 0;
    __syncthreads();
    if (t == 0) flag[0] = bad_s[0] | bad_s[1] | bad_s[2] | bad_s[3];
}

// One block per (b,n) row: LayerNorm(x) @ Wl + bl, then apply mask -> lm (f32)
__global__ __launch_bounds__(256) void ln_left_kernel(
    const float* __restrict__ x, const void* __restrict__ mask,
    const float* __restrict__ ln_g, const float* __restrict__ ln_b,
    const float* __restrict__ Wl, const float* __restrict__ bl,
    const int* __restrict__ flag, float* __restrict__ lm)
{
    const int row = blockIdx.x;          // b*NSEQ + n
    const int t = threadIdx.x;
    const int lane = t & 63, w = t >> 6;
    __shared__ float xs[DIM];
    __shared__ float red[8];

    float v = x[row * DIM + t];
    float s = v, ss = v * v;
    #pragma unroll
    for (int o = 32; o; o >>= 1) { s += __shfl_xor(s, o); ss += __shfl_xor(ss, o); }
    if (lane == 0) { red[w] = s; red[4 + w] = ss; }
    __syncthreads();
    s  = red[0] + red[1] + red[2] + red[3];
    ss = red[4] + red[5] + red[6] + red[7];
    const float mu  = s * (1.0f / DIM);
    const float var = ss * (1.0f / DIM) - mu * mu;
    const float rs  = rsqrtf(var + EPS);
    xs[t] = (v - mu) * rs * ln_g[t] + ln_b[t];
    __syncthreads();

    float acc = bl[t];
    #pragma unroll 4
    for (int k = 0; k < DIM; k += 4) {
        float4 xv = *(const float4*)&xs[k];
        acc = fmaf(xv.x, Wl[(k + 0) * HID + t], acc);
        acc = fmaf(xv.y, Wl[(k + 1) * HID + t], acc);
        acc = fmaf(xv.z, Wl[(k + 2) * HID + t], acc);
        acc = fmaf(xv.w, Wl[(k + 3) * HID + t], acc);
    }
    const int mv = flag[0] ? (int)((const unsigned char*)mask)[row]
                           : ((const int*)mask)[row];
    lm[row * HID + t] = mv ? acc : 0.0f;
}

// WoT[n][k] = bf16(Wo[k][n])
__global__ __launch_bounds__(256) void wo_transpose_kernel(
    const float* __restrict__ Wo, unsigned short* __restrict__ woT)
{
    const int n = blockIdx.x, k = threadIdx.x;
    woT[n * HID + k] = f2bf(Wo[k * HID + n]);
}

// Main fused kernel: 256 threads / 4 waves (R1-proven structure throughout).
// Symmetry: out[b,i,j,:] == out[b,j,i,:] bitwise -> compute upper-triangle
// block-pairs only; off-diagonal blocks mirror-write (j,i).
// Phase B: 16x16x16 bf16 MFMA, R1's exact k-window (k = 4*(lane>>4)+e) and
// roles (A = Y rows from LDS, B = WoT). Preferred path: the _1k builtin
// (compiler-managed hazards). Fallback: volatile asm with explicit manual
// waitstates (s_nop 1 after acc init; 2x s_nop 7 + register ties before
// the epilogue) per the CDNA manual-waitstate rules.
__global__ __launch_bounds__(256) void outer_kernel(
    const float* __restrict__ lm, const unsigned short* __restrict__ woT,
    const float* __restrict__ lno_g, const float* __restrict__ lno_b,
    const float* __restrict__ bo, float* __restrict__ out)
{
    // ---- block decode: (b, i, jt, mirror) ----
    int blk = (int)blockIdx.x;
    int b = 0;
    if (blk >= BATCH_BLOCKS) { b = 1; blk -= BATCH_BLOCKS; }
    int i, jt, mirror;
    if (blk < DIAG_BLOCKS) {
        i = blk; jt = i >> 6; mirror = 0;
    } else {
        const int r2 = blk - DIAG_BLOCKS;      // 0..1791
        const int p  = r2 >> 6;                // 0..27 pair index (bi,bj), bj>bi
        const int il = r2 & 63;
        int bi = 0, start = 0;
        #pragma unroll
        for (int bb = 0; bb < 7; ++bb) {
            const int s = bb * 7 - (bb * (bb - 1)) / 2;   // 0,7,13,18,22,25,27
            if (p >= s) { bi = bb; start = s; }
        }
        const int bj = bi + 1 + (p - start);
        i = bi * 64 + il;
        jt = bj;
        mirror = 1;
    }
    const int j0  = jt * 64;
    const int t    = threadIdx.x;
    const int lane = t & 63;
    const int w    = t >> 6;

    __shared__ __align__(16) unsigned char ybuf[64 * 512];  // 64 rows x 256 bf16

    const float4 li4 = *(const float4*)&lm[(size_t)(b * NSEQ + i) * HID + lane * 4];
    const float4 g4  = *(const float4*)&lno_g[lane * 4];
    const float4 bb4 = *(const float4*)&lno_b[lane * 4];

    // ---------------- Phase A: wave w handles local rows [16w, 16w+16)
    for (int r = 0; r < 16; ++r) {
        const int rl = w * 16 + r;
        const int j  = j0 + rl;
        float4 lj4 = *(const float4*)&lm[(size_t)(b * NSEQ + j) * HID + lane * 4];
        float4 p;
        p.x = gelu_exact(li4.x * lj4.x);
        p.y = gelu_exact(li4.y * lj4.y);
        p.z = gelu_exact(li4.z * lj4.z);
        p.w = gelu_exact(li4.w * lj4.w);
        float s  = p.x + p.y + p.z + p.w;
        float ss = p.x * p.x + p.y * p.y + p.z * p.z + p.w * p.w;
        #pragma unroll
        for (int o = 32; o; o >>= 1) { s += __shfl_xor(s, o); ss += __shfl_xor(ss, o); }
        const float mu  = s * (1.0f / HID);
        const float var = ss * (1.0f / HID) - mu * mu;
        const float rs  = rsqrtf(var + EPS);
        const float y0 = (p.x - mu) * rs * g4.x + bb4.x;
        const float y1 = (p.y - mu) * rs * g4.y + bb4.y;
        const float y2 = (p.z - mu) * rs * g4.z + bb4.z;
        const float y3 = (p.w - mu) * rs * g4.w + bb4.w;
        const unsigned int u0 = ((unsigned)f2bf(y1) << 16) | (unsigned)f2bf(y0);
        const unsigned int u1 = ((unsigned)f2bf(y3) << 16) | (unsigned)f2bf(y2);
        // XOR swizzle (flip byte bits 4..6 with row&7): kills 512B-stride conflicts
        const int off = rl * 512 + ((lane * 8) ^ ((rl & 7) << 4));
        *(uint2*)&ybuf[off] = make_uint2(u0, u1);
    }
    __syncthreads();

    // ---------------- Phase B: wave w owns output cols [64w, 64w+64)
    const int n0  = w * 64;
    const int l15 = lane & 15;
    const int q   = lane >> 4;           // 0..3

    f32x4 acc[4][4];
    #pragma unroll
    for (int mi = 0; mi < 4; ++mi)
        #pragma unroll
        for (int ni = 0; ni < 4; ++ni)
            acc[mi][ni] = (f32x4){0.f, 0.f, 0.f, 0.f};

#if !__has_builtin(__builtin_amdgcn_mfma_f32_16x16x16bf16_1k)
    // Hazard guard: tie accs into volatile asm order, then 2 waitstates
    // (VALU-write -> MFMA-srcC-read rule) before the first MFMA.
    #pragma unroll
    for (int mi = 0; mi < 4; ++mi)
        #pragma unroll
        for (int ni = 0; ni < 4; ++ni)
            asm volatile("" : "+v"(acc[mi][ni]));
    asm volatile("s_nop 1");
#endif

    #pragma unroll
    for (int kk = 0; kk < 16; ++kk) {          // K = 256 in steps of 16
        const int koff = kk * 32 + q * 8;      // byte offset in row: k = kk*16 + q*4
        bf16x4 a[4], bfr[4];
        #pragma unroll
        for (int mi = 0; mi < 4; ++mi) {
            const int rowm = mi * 16 + l15;
            a[mi] = *(const bf16x4*)&ybuf[rowm * 512 + (koff ^ ((rowm & 7) << 4))];
        }
        const int kel = kk * 16 + q * 4;
        #pragma unroll
        for (int ni = 0; ni < 4; ++ni) {
            const int col = n0 + ni * 16 + l15;
            bfr[ni] = *(const bf16x4*)&woT[col * HID + kel];
        }
        // Non-swapped (R1 roles): D[m=j][n=h]
        #pragma unroll
        for (int mi = 0; mi < 4; ++mi)
            #pragma unroll
            for (int ni = 0; ni < 4; ++ni) {
#if __has_builtin(__builtin_amdgcn_mfma_f32_16x16x16bf16_1k)
                acc[mi][ni] = __builtin_amdgcn_mfma_f32_16x16x16bf16_1k(
                    a[mi], bfr[ni], acc[mi][ni], 0, 0, 0);
#else
                asm volatile("v_mfma_f32_16x16x16_bf16 %0, %1, %2, %0"
                             : "+v"(acc[mi][ni]) : "v"(a[mi]), "v"(bfr[ni]));
#endif
            }
    }

#if !__has_builtin(__builtin_amdgcn_mfma_f32_16x16x16bf16_1k)
    // Hazard guard: 16 waitstates (MFMA-write -> VALU-read rule), then tie
    // accs to a volatile asm AFTER the nops so epilogue reads cannot hoist.
    asm volatile("s_nop 7");
    asm volatile("s_nop 7");
    #pragma unroll
    for (int mi = 0; mi < 4; ++mi)
        #pragma unroll
        for (int ni = 0; ni < 4; ++ni)
            asm volatile("" : "+v"(acc[mi][ni]));
#endif

    // Epilogue (R1-proven layout): C/D col = lane&15 -> h, row = 4q+reg -> j.
    // Primary write (b,i,j,:); off-diagonal blocks also mirror (b,j,i,:).
    const size_t base = (size_t)(b * NSEQ + i) * NSEQ * HID;
    #pragma unroll
    for (int ni = 0; ni < 4; ++ni) {
        const int col = n0 + ni * 16 + l15;
        const float boc = bo[col];
        #pragma unroll
        for (int mi = 0; mi < 4; ++mi) {
            const int rbase = j0 + mi * 16 + q * 4;
            #pragma unroll
            for (int rr = 0; rr < 4; ++rr) {
                const float val = acc[mi][ni][rr] + boc;
                out[base + (size_t)(rbase + rr) * HID + col] = val;
                if (mirror) {
                    out[((size_t)(b * NSEQ + rbase + rr) * NSEQ + i) * HID + col] = val;
                }
            }
        }
    }
}

extern "C" void kernel_launch(void* const* d_in, const int* in_sizes, int n_in,
                              void* d_out, int out_size, void* d_ws, size_t ws_size,
                              hipStream_t stream) {
    (void)in_sizes; (void)n_in; (void)out_size; (void)ws_size;
    const float* x     = (const float*)d_in[0];
    const void*  mask  = d_in[1];
    const float* ln_g  = (const float*)d_in[2];
    const float* ln_b  = (const float*)d_in[3];
    const float* Wl    = (const float*)d_in[4];
    const float* bl    = (const float*)d_in[5];
    const float* Wo    = (const float*)d_in[6];
    const float* bo    = (const float*)d_in[7];
    const float* lno_g = (const float*)d_in[8];
    const float* lno_b = (const float*)d_in[9];

    int*            flag = (int*)d_ws;
    float*          lm   = (float*)((char*)d_ws + 256);
    unsigned short* woT  = (unsigned short*)((char*)d_ws + 256 + (size_t)NB * NSEQ * HID * 4);

    detect_mask_kernel<<<1, 256, 0, stream>>>((const int*)mask, flag);
    ln_left_kernel<<<NB * NSEQ, 256, 0, stream>>>(x, mask, ln_g, ln_b, Wl, bl, flag, lm);
    wo_transpose_kernel<<<HID, 256, 0, stream>>>(Wo, woT);
    outer_kernel<<<NB * BATCH_BLOCKS, 256, 0, stream>>>(
        lm, woT, lno_g, lno_b, bo, (float*)d_out);
}

// Round 8
// 240.721 us; speedup vs baseline: 1.3793x; 1.3328x over previous
//
#include <hip/hip_runtime.h>
#include <stdint.h>

#define DIM 256
#define HID 256
#define NSEQ 512
#define NB 2
#define EPS 1e-5f

typedef __attribute__((ext_vector_type(4))) float f32x4;
typedef __attribute__((ext_vector_type(4))) short bf16x4;

// Blocks per batch: 512 diagonal (i, jt=i>>6) + 28 pairs * 64 rows = 2304
#define DIAG_BLOCKS 512
#define BATCH_BLOCKS 2304

__device__ __forceinline__ unsigned short f2bf(float f) {
    unsigned int u = __float_as_uint(f);
    u += 0x7fffu + ((u >> 16) & 1u);
    return (unsigned short)(u >> 16);
}

// gelu via Abramowitz-Stegun 7.1.26 erf (|abs err| <= 1.5e-7), branchless,
// HW rcp + exp2. Re-trial on hazard-free builtin base (R2's failure is now
// attributed to its asm-schedule reroll, not this poly).
__device__ __forceinline__ float gelu_fast(float x) {
    const float z  = x * 0.7071067811865476f;
    const float az = fabsf(z);
    const float t  = __builtin_amdgcn_rcpf(fmaf(0.3275911f, az, 1.0f));
    float p = fmaf(1.061405429f, t, -1.453152027f);
    p = fmaf(p, t,  1.421413741f);
    p = fmaf(p, t, -0.284496736f);
    p = fmaf(p, t,  0.254829592f);
    p = p * t;
    const float e = __builtin_amdgcn_exp2f(az * az * -1.4426950408889634f);
    float erfv = fmaf(-p, e, 1.0f);
    erfv = copysignf(erfv, z);
    return 0.5f * x * (1.0f + erfv);
}

// Fused prep: mask-layout probe + LayerNorm(x)@Wl+bl+mask -> lm; blocks with
// row < HID also emit woT[n][k] = bf16(Wo[k][n]).
__global__ __launch_bounds__(256) void prep_kernel(
    const float* __restrict__ x, const void* __restrict__ mask,
    const float* __restrict__ ln_g, const float* __restrict__ ln_b,
    const float* __restrict__ Wl, const float* __restrict__ bl,
    const float* __restrict__ Wo,
    float* __restrict__ lm, unsigned short* __restrict__ woT)
{
    const int row = blockIdx.x;          // b*NSEQ + n
    const int t = threadIdx.x;
    const int lane = t & 63, w = t >> 6;
    __shared__ float xs[DIM];
    __shared__ float red[8];
    __shared__ int bad_s[4];

    // mask layout probe: first 1024 bytes (safe under both layouts).
    {
        const int v = ((const int*)mask)[t];
        unsigned long long bm = __ballot((v & ~1) != 0);
        if (lane == 0) bad_s[w] = (bm != 0ull) ? 1 : 0;
    }

    float v = x[row * DIM + t];
    float s = v, ss = v * v;
    #pragma unroll
    for (int o = 32; o; o >>= 1) { s += __shfl_xor(s, o); ss += __shfl_xor(ss, o); }
    if (lane == 0) { red[w] = s; red[4 + w] = ss; }
    __syncthreads();
    s  = red[0] + red[1] + red[2] + red[3];
    ss = red[4] + red[5] + red[6] + red[7];
    const float mu  = s * (1.0f / DIM);
    const float var = ss * (1.0f / DIM) - mu * mu;
    const float rs  = rsqrtf(var + EPS);
    xs[t] = (v - mu) * rs * ln_g[t] + ln_b[t];
    __syncthreads();

    float acc = bl[t];
    #pragma unroll 4
    for (int k = 0; k < DIM; k += 4) {
        float4 xv = *(const float4*)&xs[k];
        acc = fmaf(xv.x, Wl[(k + 0) * HID + t], acc);
        acc = fmaf(xv.y, Wl[(k + 1) * HID + t], acc);
        acc = fmaf(xv.z, Wl[(k + 2) * HID + t], acc);
        acc = fmaf(xv.w, Wl[(k + 3) * HID + t], acc);
    }
    const int packed = bad_s[0] | bad_s[1] | bad_s[2] | bad_s[3];
    const int mv = packed ? (int)((const unsigned char*)mask)[row]
                          : ((const int*)mask)[row];
    lm[row * HID + t] = mv ? acc : 0.0f;

    if (row < HID) {                      // transpose duty for first 256 blocks
        woT[row * HID + t] = f2bf(Wo[t * HID + row]);
    }
}

// Main fused kernel: 256 threads / 4 waves.
// Symmetry (R7-verified): out[b,i,j,:] == out[b,j,i,:] bitwise -> upper
// triangle only; off-diagonal blocks mirror-write.
// Phase B: 16x16x16 bf16 MFMA (R1/R7-proven input pairing), SWAPPED roles
// (A = WoT frag -> M=h, B = Y frag -> N=j). k-pairing invariant under swap
// since sigma_A == sigma_B for this shape. D: j = l&15, h = 4*(l>>4)+reg ->
// float4 stores along H for primary AND mirror.
__global__ __launch_bounds__(256) void outer_kernel(
    const float* __restrict__ lm, const unsigned short* __restrict__ woT,
    const float* __restrict__ lno_g, const float* __restrict__ lno_b,
    const float* __restrict__ bo, float* __restrict__ out)
{
    // ---- block decode: (b, i, jt, mirror) ----
    int blk = (int)blockIdx.x;
    int b = 0;
    if (blk >= BATCH_BLOCKS) { b = 1; blk -= BATCH_BLOCKS; }
    int i, jt, mirror;
    if (blk < DIAG_BLOCKS) {
        i = blk; jt = i >> 6; mirror = 0;
    } else {
        const int r2 = blk - DIAG_BLOCKS;      // 0..1791
        const int p  = r2 >> 6;                // 0..27 pair index (bi,bj), bj>bi
        const int il = r2 & 63;
        int bi = 0, start = 0;
        #pragma unroll
        for (int bb = 0; bb < 7; ++bb) {
            const int s = bb * 7 - (bb * (bb - 1)) / 2;   // 0,7,13,18,22,25,27
            if (p >= s) { bi = bb; start = s; }
        }
        const int bj = bi + 1 + (p - start);
        i = bi * 64 + il;
        jt = bj;
        mirror = 1;
    }
    const int j0  = jt * 64;
    const int t    = threadIdx.x;
    const int lane = t & 63;
    const int w    = t >> 6;

    __shared__ __align__(16) unsigned char ybuf[64 * 512];  // 64 rows x 256 bf16

    const float4 li4 = *(const float4*)&lm[(size_t)(b * NSEQ + i) * HID + lane * 4];
    const float4 g4  = *(const float4*)&lno_g[lane * 4];
    const float4 bb4 = *(const float4*)&lno_b[lane * 4];

    // ---------------- Phase A: wave w handles local rows [16w, 16w+16)
    #pragma unroll 4
    for (int r = 0; r < 16; ++r) {
        const int rl = w * 16 + r;
        const int j  = j0 + rl;
        float4 lj4 = *(const float4*)&lm[(size_t)(b * NSEQ + j) * HID + lane * 4];
        float4 p;
        p.x = gelu_fast(li4.x * lj4.x);
        p.y = gelu_fast(li4.y * lj4.y);
        p.z = gelu_fast(li4.z * lj4.z);
        p.w = gelu_fast(li4.w * lj4.w);
        float s  = p.x + p.y + p.z + p.w;
        float ss = p.x * p.x + p.y * p.y + p.z * p.z + p.w * p.w;
        #pragma unroll
        for (int o = 32; o; o >>= 1) { s += __shfl_xor(s, o); ss += __shfl_xor(ss, o); }
        const float mu  = s * (1.0f / HID);
        const float var = ss * (1.0f / HID) - mu * mu;
        const float rs  = rsqrtf(var + EPS);
        const float y0 = (p.x - mu) * rs * g4.x + bb4.x;
        const float y1 = (p.y - mu) * rs * g4.y + bb4.y;
        const float y2 = (p.z - mu) * rs * g4.z + bb4.z;
        const float y3 = (p.w - mu) * rs * g4.w + bb4.w;
        const unsigned int u0 = ((unsigned)f2bf(y1) << 16) | (unsigned)f2bf(y0);
        const unsigned int u1 = ((unsigned)f2bf(y3) << 16) | (unsigned)f2bf(y2);
        // XOR swizzle (flip byte bits 4..6 with row&7): kills 512B-stride conflicts
        const int off = rl * 512 + ((lane * 8) ^ ((rl & 7) << 4));
        *(uint2*)&ybuf[off] = make_uint2(u0, u1);
    }
    __syncthreads();

    // ---------------- Phase B: wave w owns output cols [64w, 64w+64)
    const int n0  = w * 64;
    const int l15 = lane & 15;
    const int q   = lane >> 4;           // 0..3

    f32x4 acc[4][4];
    #pragma unroll
    for (int mi = 0; mi < 4; ++mi)
        #pragma unroll
        for (int ni = 0; ni < 4; ++ni)
            acc[mi][ni] = (f32x4){0.f, 0.f, 0.f, 0.f};

#if !__has_builtin(__builtin_amdgcn_mfma_f32_16x16x16bf16_1k)
    #pragma unroll
    for (int mi = 0; mi < 4; ++mi)
        #pragma unroll
        for (int ni = 0; ni < 4; ++ni)
            asm volatile("" : "+v"(acc[mi][ni]));
    asm volatile("s_nop 1");
#endif

    #pragma unroll
    for (int kk = 0; kk < 16; ++kk) {          // K = 256 in steps of 16
        const int koff = kk * 32 + q * 8;      // byte offset in row: k = kk*16 + q*4
        bf16x4 a[4], bfr[4];
        #pragma unroll
        for (int mi = 0; mi < 4; ++mi) {
            const int rowm = mi * 16 + l15;
            a[mi] = *(const bf16x4*)&ybuf[rowm * 512 + (koff ^ ((rowm & 7) << 4))];
        }
        const int kel = kk * 16 + q * 4;
        #pragma unroll
        for (int ni = 0; ni < 4; ++ni) {
            const int col = n0 + ni * 16 + l15;
            bfr[ni] = *(const bf16x4*)&woT[col * HID + kel];
        }
        // SWAPPED roles: A = WoT (M=h), B = Y (N=j)
        #pragma unroll
        for (int mi = 0; mi < 4; ++mi)
            #pragma unroll
            for (int ni = 0; ni < 4; ++ni) {
#if __has_builtin(__builtin_amdgcn_mfma_f32_16x16x16bf16_1k)
                acc[mi][ni] = __builtin_amdgcn_mfma_f32_16x16x16bf16_1k(
                    bfr[ni], a[mi], acc[mi][ni], 0, 0, 0);
#else
                asm volatile("v_mfma_f32_16x16x16_bf16 %0, %1, %2, %0"
                             : "+v"(acc[mi][ni]) : "v"(bfr[ni]), "v"(a[mi]));
#endif
            }
    }

#if !__has_builtin(__builtin_amdgcn_mfma_f32_16x16x16bf16_1k)
    asm volatile("s_nop 7");
    asm volatile("s_nop 7");
    #pragma unroll
    for (int mi = 0; mi < 4; ++mi)
        #pragma unroll
        for (int ni = 0; ni < 4; ++ni)
            asm volatile("" : "+v"(acc[mi][ni]));
#endif

    // Epilogue: lane l, reg r -> j = j0 + mi*16 + (l&15), h = n0 + ni*16 + 4q + r
    const size_t base = (size_t)(b * NSEQ + i) * NSEQ * HID;
    #pragma unroll
    for (int mi = 0; mi < 4; ++mi) {
        const int j = j0 + mi * 16 + l15;
        const size_t prow = base + (size_t)j * HID;
        const size_t mrow = ((size_t)(b * NSEQ + j) * NSEQ + i) * HID;
        #pragma unroll
        for (int ni = 0; ni < 4; ++ni) {
            const int h0 = n0 + ni * 16 + q * 4;
            const float4 bo4 = *(const float4*)&bo[h0];
            float4 o;
            o.x = acc[mi][ni][0] + bo4.x;
            o.y = acc[mi][ni][1] + bo4.y;
            o.z = acc[mi][ni][2] + bo4.z;
            o.w = acc[mi][ni][3] + bo4.w;
            *(float4*)&out[prow + h0] = o;
            if (mirror) *(float4*)&out[mrow + h0] = o;
        }
    }
}

extern "C" void kernel_launch(void* const* d_in, const int* in_sizes, int n_in,
                              void* d_out, int out_size, void* d_ws, size_t ws_size,
                              hipStream_t stream) {
    (void)in_sizes; (void)n_in; (void)out_size; (void)ws_size;
    const float* x     = (const float*)d_in[0];
    const void*  mask  = d_in[1];
    const float* ln_g  = (const float*)d_in[2];
    const float* ln_b  = (const float*)d_in[3];
    const float* Wl    = (const float*)d_in[4];
    const float* bl    = (const float*)d_in[5];
    const float* Wo    = (const float*)d_in[6];
    const float* bo    = (const float*)d_in[7];
    const float* lno_g = (const float*)d_in[8];
    const float* lno_b = (const float*)d_in[9];

    float*          lm  = (float*)d_ws;
    unsigned short* woT = (unsigned short*)((char*)d_ws + (size_t)NB * NSEQ * HID * 4);

    prep_kernel<<<NB * NSEQ, 256, 0, stream>>>(x, mask, ln_g, ln_b, Wl, bl, Wo, lm, woT);
    outer_kernel<<<NB * BATCH_BLOCKS, 256, 0, stream>>>(
        lm, woT, lno_g, lno_b, bo, (float*)d_out);
}

// Round 9
// 191.238 us; speedup vs baseline: 1.7362x; 1.2588x over previous
//
#include <hip/hip_runtime.h>
#include <stdint.h>

#define DIM 256
#define HID 256
#define NSEQ 512
#define NB 2
#define EPS 1e-5f

typedef __attribute__((ext_vector_type(4))) float f32x4;
typedef __attribute__((ext_vector_type(4))) short bf16x4;
typedef __attribute__((ext_vector_type(8))) short bf16x8;

// Blocks per batch: 512 diagonal (i, jt=i>>6) + 28 pairs * 64 rows = 2304
#define DIAG_BLOCKS 512
#define BATCH_BLOCKS 2304

__device__ __forceinline__ unsigned short f2bf(float f) {
    unsigned int u = __float_as_uint(f);
    u += 0x7fffu + ((u >> 16) & 1u);
    return (unsigned short)(u >> 16);
}

// gelu via Abramowitz-Stegun 7.1.26 erf (|abs err| <= 1.5e-7), branchless,
// HW rcp + exp2. R8-proven at the bf16 absmax floor (0.015625).
__device__ __forceinline__ float gelu_fast(float x) {
    const float z  = x * 0.7071067811865476f;
    const float az = fabsf(z);
    const float t  = __builtin_amdgcn_rcpf(fmaf(0.3275911f, az, 1.0f));
    float p = fmaf(1.061405429f, t, -1.453152027f);
    p = fmaf(p, t,  1.421413741f);
    p = fmaf(p, t, -0.284496736f);
    p = fmaf(p, t,  0.254829592f);
    p = p * t;
    const float e = __builtin_amdgcn_exp2f(az * az * -1.4426950408889634f);
    float erfv = fmaf(-p, e, 1.0f);
    erfv = copysignf(erfv, z);
    return 0.5f * x * (1.0f + erfv);
}

// Paired-k position: element k -> 32*(k>>5) + 8*((k>>2)&3) + 4*((k>>4)&1) + (k&3).
// One 16B read at (kk2,q) then yields k-windows of kk=2*kk2 (lo) and 2*kk2+1 (hi).
__device__ __forceinline__ int pairpos(int k) {
    return ((k >> 5) << 5) + (((k >> 2) & 3) << 3) + (((k >> 4) & 1) << 2) + (k & 3);
}

// Fused prep: mask-layout probe + LayerNorm(x)@Wl+bl+mask -> lm; blocks with
// row < HID also emit woTp[n][pairpos(k)] = bf16(Wo[k][n]).
__global__ __launch_bounds__(256) void prep_kernel(
    const float* __restrict__ x, const void* __restrict__ mask,
    const float* __restrict__ ln_g, const float* __restrict__ ln_b,
    const float* __restrict__ Wl, const float* __restrict__ bl,
    const float* __restrict__ Wo,
    float* __restrict__ lm, unsigned short* __restrict__ woTp)
{
    const int row = blockIdx.x;          // b*NSEQ + n
    const int t = threadIdx.x;
    const int lane = t & 63, w = t >> 6;
    __shared__ float xs[DIM];
    __shared__ float red[8];
    __shared__ int bad_s[4];

    // mask layout probe: first 1024 bytes (safe under both layouts).
    {
        const int v = ((const int*)mask)[t];
        unsigned long long bm = __ballot((v & ~1) != 0);
        if (lane == 0) bad_s[w] = (bm != 0ull) ? 1 : 0;
    }

    float v = x[row * DIM + t];
    float s = v, ss = v * v;
    #pragma unroll
    for (int o = 32; o; o >>= 1) { s += __shfl_xor(s, o); ss += __shfl_xor(ss, o); }
    if (lane == 0) { red[w] = s; red[4 + w] = ss; }
    __syncthreads();
    s  = red[0] + red[1] + red[2] + red[3];
    ss = red[4] + red[5] + red[6] + red[7];
    const float mu  = s * (1.0f / DIM);
    const float var = ss * (1.0f / DIM) - mu * mu;
    const float rs  = rsqrtf(var + EPS);
    xs[t] = (v - mu) * rs * ln_g[t] + ln_b[t];
    __syncthreads();

    float acc = bl[t];
    #pragma unroll 4
    for (int k = 0; k < DIM; k += 4) {
        float4 xv = *(const float4*)&xs[k];
        acc = fmaf(xv.x, Wl[(k + 0) * HID + t], acc);
        acc = fmaf(xv.y, Wl[(k + 1) * HID + t], acc);
        acc = fmaf(xv.z, Wl[(k + 2) * HID + t], acc);
        acc = fmaf(xv.w, Wl[(k + 3) * HID + t], acc);
    }
    const int packed = bad_s[0] | bad_s[1] | bad_s[2] | bad_s[3];
    const int mv = packed ? (int)((const unsigned char*)mask)[row]
                          : ((const int*)mask)[row];
    lm[row * HID + t] = mv ? acc : 0.0f;

    if (row < HID) {                      // transpose duty for first 256 blocks
        woTp[row * HID + pairpos(t)] = f2bf(Wo[t * HID + row]);
    }
}

// Main fused kernel: 256 threads / 4 waves (R8-proven structure).
// Symmetry (R7-verified): out[b,i,j,:] == out[b,j,i,:] -> upper triangle only;
// off-diagonal blocks mirror-write.
// Phase B: 16x16x16 bf16 MFMA with R8's proven roles (A=WoT frag -> M=h,
// B=Y frag -> N=j) and k-windows; paired-k layout upgrades loads to
// ds_read_b128 / global dwordx4 (half the memory instructions).
__global__ __launch_bounds__(256) void outer_kernel(
    const float* __restrict__ lm, const unsigned short* __restrict__ woTp,
    const float* __restrict__ lno_g, const float* __restrict__ lno_b,
    const float* __restrict__ bo, float* __restrict__ out)
{
    // ---- block decode: (b, i, jt, mirror) ----
    int blk = (int)blockIdx.x;
    int b = 0;
    if (blk >= BATCH_BLOCKS) { b = 1; blk -= BATCH_BLOCKS; }
    int i, jt, mirror;
    if (blk < DIAG_BLOCKS) {
        i = blk; jt = i >> 6; mirror = 0;
    } else {
        const int r2 = blk - DIAG_BLOCKS;      // 0..1791
        const int p  = r2 >> 6;                // 0..27 pair index (bi,bj), bj>bi
        const int il = r2 & 63;
        int bi = 0, start = 0;
        #pragma unroll
        for (int bb = 0; bb < 7; ++bb) {
            const int s = bb * 7 - (bb * (bb - 1)) / 2;   // 0,7,13,18,22,25,27
            if (p >= s) { bi = bb; start = s; }
        }
        const int bj = bi + 1 + (p - start);
        i = bi * 64 + il;
        jt = bj;
        mirror = 1;
    }
    const int j0  = jt * 64;
    const int t    = threadIdx.x;
    const int lane = t & 63;
    const int w    = t >> 6;

    __shared__ __align__(16) unsigned char ybuf[64 * 512];  // 64 rows x 256 bf16 (paired-k)

    const float4 li4 = *(const float4*)&lm[(size_t)(b * NSEQ + i) * HID + lane * 4];
    const float4 g4  = *(const float4*)&lno_g[lane * 4];
    const float4 bb4 = *(const float4*)&lno_b[lane * 4];

    // Paired-k write slot for this lane's k = 4*lane .. 4*lane+3 (8 bytes):
    const int wrb = ((lane >> 3) << 6) + ((lane & 3) << 4) + (((lane >> 2) & 1) << 3);

    // ---------------- Phase A: wave w handles local rows [16w, 16w+16)
    #pragma unroll 4
    for (int r = 0; r < 16; ++r) {
        const int rl = w * 16 + r;
        const int j  = j0 + rl;
        float4 lj4 = *(const float4*)&lm[(size_t)(b * NSEQ + j) * HID + lane * 4];
        float4 p;
        p.x = gelu_fast(li4.x * lj4.x);
        p.y = gelu_fast(li4.y * lj4.y);
        p.z = gelu_fast(li4.z * lj4.z);
        p.w = gelu_fast(li4.w * lj4.w);
        float s  = p.x + p.y + p.z + p.w;
        float ss = p.x * p.x + p.y * p.y + p.z * p.z + p.w * p.w;
        #pragma unroll
        for (int o = 32; o; o >>= 1) { s += __shfl_xor(s, o); ss += __shfl_xor(ss, o); }
        const float mu  = s * (1.0f / HID);
        const float var = ss * (1.0f / HID) - mu * mu;
        const float rs  = rsqrtf(var + EPS);
        const float y0 = (p.x - mu) * rs * g4.x + bb4.x;
        const float y1 = (p.y - mu) * rs * g4.y + bb4.y;
        const float y2 = (p.z - mu) * rs * g4.z + bb4.z;
        const float y3 = (p.w - mu) * rs * g4.w + bb4.w;
        const unsigned int u0 = ((unsigned)f2bf(y1) << 16) | (unsigned)f2bf(y0);
        const unsigned int u1 = ((unsigned)f2bf(y3) << 16) | (unsigned)f2bf(y2);
        // XOR swizzle on byte bits [6:4] with row&7: kills 512B-stride conflicts
        const int off = rl * 512 + (wrb ^ ((rl & 7) << 4));
        *(uint2*)&ybuf[off] = make_uint2(u0, u1);
    }
    __syncthreads();

    // ---------------- Phase B: wave w owns output cols [64w, 64w+64)
    const int n0  = w * 64;
    const int l15 = lane & 15;
    const int q   = lane >> 4;           // 0..3

    f32x4 acc[4][4];
    #pragma unroll
    for (int mi = 0; mi < 4; ++mi)
        #pragma unroll
        for (int ni = 0; ni < 4; ++ni)
            acc[mi][ni] = (f32x4){0.f, 0.f, 0.f, 0.f};

#if !__has_builtin(__builtin_amdgcn_mfma_f32_16x16x16bf16_1k)
    #pragma unroll
    for (int mi = 0; mi < 4; ++mi)
        #pragma unroll
        for (int ni = 0; ni < 4; ++ni)
            asm volatile("" : "+v"(acc[mi][ni]));
    asm volatile("s_nop 1");
#endif

    #pragma unroll
    for (int kk2 = 0; kk2 < 8; ++kk2) {        // K = 256 in steps of 32 (2 kk each)
        const int pb = kk2 * 64 + q * 16;      // paired-k byte offset within row
        bf16x8 a8[4], b8[4];
        #pragma unroll
        for (int mi = 0; mi < 4; ++mi) {
            const int rowm = mi * 16 + l15;
            a8[mi] = *(const bf16x8*)&ybuf[rowm * 512 + (pb ^ ((rowm & 7) << 4))];
        }
        #pragma unroll
        for (int ni = 0; ni < 4; ++ni) {
            const int col = n0 + ni * 16 + l15;
            b8[ni] = *(const bf16x8*)&woTp[col * HID + kk2 * 32 + q * 8];
        }
        // lo halves = kk even, hi halves = kk odd; same k-windows as R8.
        #pragma unroll
        for (int mi = 0; mi < 4; ++mi) {
            const bf16x4 alo = __builtin_shufflevector(a8[mi], a8[mi], 0, 1, 2, 3);
            const bf16x4 ahi = __builtin_shufflevector(a8[mi], a8[mi], 4, 5, 6, 7);
            #pragma unroll
            for (int ni = 0; ni < 4; ++ni) {
                const bf16x4 blo = __builtin_shufflevector(b8[ni], b8[ni], 0, 1, 2, 3);
                const bf16x4 bhi = __builtin_shufflevector(b8[ni], b8[ni], 4, 5, 6, 7);
#if __has_builtin(__builtin_amdgcn_mfma_f32_16x16x16bf16_1k)
                acc[mi][ni] = __builtin_amdgcn_mfma_f32_16x16x16bf16_1k(
                    blo, alo, acc[mi][ni], 0, 0, 0);
                acc[mi][ni] = __builtin_amdgcn_mfma_f32_16x16x16bf16_1k(
                    bhi, ahi, acc[mi][ni], 0, 0, 0);
#else
                asm volatile("v_mfma_f32_16x16x16_bf16 %0, %1, %2, %0"
                             : "+v"(acc[mi][ni]) : "v"(blo), "v"(alo));
                asm volatile("v_mfma_f32_16x16x16_bf16 %0, %1, %2, %0"
                             : "+v"(acc[mi][ni]) : "v"(bhi), "v"(ahi));
#endif
            }
        }
    }

#if !__has_builtin(__builtin_amdgcn_mfma_f32_16x16x16bf16_1k)
    asm volatile("s_nop 7");
    asm volatile("s_nop 7");
    #pragma unroll
    for (int mi = 0; mi < 4; ++mi)
        #pragma unroll
        for (int ni = 0; ni < 4; ++ni)
            asm volatile("" : "+v"(acc[mi][ni]));
#endif

    // Epilogue (R8-proven): lane l, reg r -> j = j0 + mi*16 + (l&15),
    // h = n0 + ni*16 + 4q + r. float4 stores for primary and mirror.
    const size_t base = (size_t)(b * NSEQ + i) * NSEQ * HID;
    #pragma unroll
    for (int mi = 0; mi < 4; ++mi) {
        const int j = j0 + mi * 16 + l15;
        const size_t prow = base + (size_t)j * HID;
        const size_t mrow = ((size_t)(b * NSEQ + j) * NSEQ + i) * HID;
        #pragma unroll
        for (int ni = 0; ni < 4; ++ni) {
            const int h0 = n0 + ni * 16 + q * 4;
            const float4 bo4 = *(const float4*)&bo[h0];
            float4 o;
            o.x = acc[mi][ni][0] + bo4.x;
            o.y = acc[mi][ni][1] + bo4.y;
            o.z = acc[mi][ni][2] + bo4.z;
            o.w = acc[mi][ni][3] + bo4.w;
            *(float4*)&out[prow + h0] = o;
            if (mirror) *(float4*)&out[mrow + h0] = o;
        }
    }
}

extern "C" void kernel_launch(void* const* d_in, const int* in_sizes, int n_in,
                              void* d_out, int out_size, void* d_ws, size_t ws_size,
                              hipStream_t stream) {
    (void)in_sizes; (void)n_in; (void)out_size; (void)ws_size;
    const float* x     = (const float*)d_in[0];
    const void*  mask  = d_in[1];
    const float* ln_g  = (const float*)d_in[2];
    const float* ln_b  = (const float*)d_in[3];
    const float* Wl    = (const float*)d_in[4];
    const float* bl    = (const float*)d_in[5];
    const float* Wo    = (const float*)d_in[6];
    const float* bo    = (const float*)d_in[7];
    const float* lno_g = (const float*)d_in[8];
    const float* lno_b = (const float*)d_in[9];

    float*          lm   = (float*)d_ws;
    unsigned short* woTp = (unsigned short*)((char*)d_ws + (size_t)NB * NSEQ * HID * 4);

    prep_kernel<<<NB * NSEQ, 256, 0, stream>>>(x, mask, ln_g, ln_b, Wl, bl, Wo, lm, woTp);
    outer_kernel<<<NB * BATCH_BLOCKS, 256, 0, stream>>>(
        lm, woTp, lno_g, lno_b, bo, (float*)d_out);
}